// Round 2
// baseline (1202.308 us; speedup 1.0000x reference)
//
#include <hip/hip_runtime.h>

// ContinuousLearningLayer: pooled[i][j] = any_{k in [j-25, j+25]} (|in[i] - w[k]| < 0.1)
// in: 1024 fp32, w: 262144 fp32, out: [1024, 262144] fp32 in {0,1}
//
// Two-kernel pipeline:
//  K1: ballot -> predicate bits, radius-25 dilation via 128-bit shift-OR,
//      store dilated 64-bit words to d_ws (32 MB bitmask).
//  K2: pure streaming expansion bitmask -> fp32 (no LDS, no barriers),
//      targeting memset-class write BW (~6.2 TB/s measured via fill).

static constexpr int N_ROWS   = 1024;
static constexpr int M_W      = 262144;
static constexpr int CHUNK    = 16384;           // elements per K1 block
static constexpr int NWORDS   = CHUNK / 64;      // 256 dilated words per K1 block
static constexpr int TOTW     = NWORDS + 2;      // +1 halo word each side
static constexpr int WORDS_PER_ROW = M_W / 64;   // 4096
static constexpr float THRESH = 0.1f;
static constexpr size_t MASK_BYTES = (size_t)N_ROWS * WORDS_PER_ROW * 8;  // 32 MB

// ---------------- K1: bitmask build ----------------
__global__ __launch_bounds__(256) void cll_mask_kernel(const float* __restrict__ in,
                                                       const float* __restrict__ wm,
                                                       unsigned long long* __restrict__ mask) {
    __shared__ unsigned long long words[TOTW];

    const int tid  = threadIdx.x;
    const int wave = tid >> 6;
    const int lane = tid & 63;
    const int row  = blockIdx.y;
    const int chunkBase = blockIdx.x * CHUNK;

    const float x = in[row];

    // Contiguous per-wave word ranges; unroll 4 so 4 loads are in flight.
    const int per    = (TOTW + 3) / 4;                       // 65
    const int wstart = wave * per;
    const int wend   = (wstart + per < TOTW) ? wstart + per : TOTW;
    for (int t = wstart; t < wend; t += 4) {
        #pragma unroll
        for (int u = 0; u < 4; ++u) {
            const int wi = t + u;
            if (wi < wend) {                                  // wave-uniform branch
                const int j = chunkBase - 64 + wi * 64 + lane;
                bool pred = false;
                if (j >= 0 && j < M_W) pred = fabsf(wm[j] - x) < THRESH;
                const unsigned long long b = __ballot(pred);
                if (lane == 0) words[wi] = b;
            }
        }
    }
    __syncthreads();

    // Radius-25 dilation: output word t needs stream bits [t*64+39, t*64+167)
    // relative to array bit 0 (array bit p <-> global j = chunkBase - 64 + p).
    const int t = tid;
    const unsigned long long lo  = words[t];
    const unsigned long long mid = words[t + 1];
    const unsigned long long hi  = words[t + 2];
    __uint128_t z = ((__uint128_t)(lo >> 39))
                  | ((__uint128_t)mid << 25)
                  | ((__uint128_t)hi << 89);
    z |= z >> 1;
    z |= z >> 2;
    z |= z >> 4;
    z |= z >> 8;
    z |= z >> 16;
    z |= z >> 19;   // union covers shifts 0..50

    mask[(long long)row * WORDS_PER_ROW + blockIdx.x * NWORDS + t] =
        (unsigned long long)z;
}

// ---------------- K2: bitmask -> fp32 expansion (pure streaming) ----------------
// Global bit index b <-> out element b (out is row-major contiguous, and the
// mask layout row*4096 + word is exactly (element>>6)), so indexing is flat.
__global__ __launch_bounds__(256) void cll_expand_kernel(const unsigned long long* __restrict__ mask,
                                                         uint4* __restrict__ out) {
    const int tid = threadIdx.x;
    // Each block covers 4096 consecutive float4 (64 KB out, 256 mask words).
    const int base = blockIdx.x * 4096 + tid;
    #pragma unroll
    for (int it = 0; it < 16; ++it) {
        const int g = base + it * 256;                 // float4 index
        const unsigned long long w = mask[g >> 4];     // 16 lanes share a word
        const unsigned b4 = (unsigned)(w >> ((g & 15) * 4)) & 0xFu;
        uint4 v;
        v.x = (b4 & 1u) ? 0x3F800000u : 0u;
        v.y = (b4 & 2u) ? 0x3F800000u : 0u;
        v.z = (b4 & 4u) ? 0x3F800000u : 0u;
        v.w = (b4 & 8u) ? 0x3F800000u : 0u;
        out[g] = v;
    }
}

// ---------------- Fallback: original fused kernel (if ws too small) ----------------
__global__ __launch_bounds__(256) void cll_fused_kernel(const float* __restrict__ in,
                                                        const float* __restrict__ wm,
                                                        float* __restrict__ out) {
    __shared__ unsigned long long words[TOTW];
    __shared__ unsigned long long dil[NWORDS];

    const int tid  = threadIdx.x;
    const int wave = tid >> 6;
    const int lane = tid & 63;
    const int row  = blockIdx.y;
    const int chunkBase = blockIdx.x * CHUNK;
    const float x = in[row];

    for (int wIdx = wave; wIdx < TOTW; wIdx += 4) {
        const int j = chunkBase - 64 + wIdx * 64 + lane;
        bool pred = false;
        if (j >= 0 && j < M_W) pred = fabsf(wm[j] - x) < THRESH;
        const unsigned long long b = __ballot(pred);
        if (lane == 0) words[wIdx] = b;
    }
    __syncthreads();
    {
        const int t = tid;
        const unsigned long long lo  = words[t];
        const unsigned long long mid = words[t + 1];
        const unsigned long long hi  = words[t + 2];
        __uint128_t z = ((__uint128_t)(lo >> 39))
                      | ((__uint128_t)mid << 25)
                      | ((__uint128_t)hi << 89);
        z |= z >> 1; z |= z >> 2; z |= z >> 4;
        z |= z >> 8; z |= z >> 16; z |= z >> 19;
        dil[t] = (unsigned long long)z;
    }
    __syncthreads();
    float* orow = out + (long long)row * M_W + chunkBase;
    #pragma unroll
    for (int it = 0; it < CHUNK / 1024; ++it) {
        const int e = it * 1024 + tid * 4;
        const unsigned long long wbits = dil[e >> 6];
        const unsigned b4 = (unsigned)(wbits >> (e & 63)) & 0xFu;
        float4 v;
        v.x = (float)(b4 & 1u);
        v.y = (float)((b4 >> 1) & 1u);
        v.z = (float)((b4 >> 2) & 1u);
        v.w = (float)((b4 >> 3) & 1u);
        *(float4*)(orow + e) = v;
    }
}

extern "C" void kernel_launch(void* const* d_in, const int* in_sizes, int n_in,
                              void* d_out, int out_size, void* d_ws, size_t ws_size,
                              hipStream_t stream) {
    const float* in = (const float*)d_in[0];    // input_features (2,512) fp32
    const float* wm = (const float*)d_in[1];    // weight_matrix (512,512) fp32
    float* out = (float*)d_out;

    if (ws_size >= MASK_BYTES) {
        unsigned long long* mask = (unsigned long long*)d_ws;
        dim3 grid1(M_W / CHUNK, N_ROWS);        // (16, 1024)
        cll_mask_kernel<<<grid1, 256, 0, stream>>>(in, wm, mask);
        const int n_f4 = (N_ROWS * M_W) / 4;    // 67,108,864
        cll_expand_kernel<<<n_f4 / 4096, 256, 0, stream>>>(mask, (uint4*)out);
    } else {
        dim3 grid(M_W / CHUNK, N_ROWS);
        cll_fused_kernel<<<grid, 256, 0, stream>>>(in, wm, out);
    }
}

// Round 3
// 1044.411 us; speedup vs baseline: 1.1512x; 1.1512x over previous
//
#include <hip/hip_runtime.h>

// ContinuousLearningLayer: pooled[i][j] = any_{k in [j-25, j+25]} (|in[i] - w[k]| < 0.1)
// in: 1024 fp32 (flattened (2,512)), w: 262144 fp32, out: [1024, 262144] fp32 in {0,1}
//
// Fused single kernel, restructured mask build:
//  Phase 1: float4 loads; each thread tests 16 weights, packs a 16-bit
//           predicate group into LDS (5 independent iterations — no serial
//           ballot chain).
//  Phase 2: raw 64-bit word = one 8 B LDS read (4 ushorts); radius-25
//           dilation via 128-bit shift-OR; dilated word to LDS.
//  Phase 3: bit -> fp32 expansion, coalesced 16 B/lane stores (1 KB/wave).
// Memory-bound on the 1.07 GB output write (~171 us at fill-rate 6.2 TB/s).

static constexpr int N_ROWS   = 1024;
static constexpr int M_W      = 262144;
static constexpr int CHUNK    = 16384;          // outputs per block
static constexpr int NWORDS   = CHUNK / 64;     // 256 dilated words
static constexpr int NGROUPS  = (NWORDS + 2) * 4;  // 1032 16-bit predicate groups
static constexpr float THRESH = 0.1f;

__global__ __launch_bounds__(256) void cll_fused2_kernel(const float* __restrict__ in,
                                                         const float* __restrict__ wm,
                                                         float* __restrict__ out) {
    // preds: group g covers weights j = chunkBase - 64 + 16*g .. +15
    __shared__ unsigned short preds[NGROUPS];          // 2064 B (8 B aligned)
    __shared__ unsigned long long dil[NWORDS];         // 2048 B

    const int tid = threadIdx.x;
    const int row = blockIdx.y;
    const int chunkBase = blockIdx.x * CHUNK;
    const float x = in[row];

    // ---- Phase 1: predicate groups via float4 loads.
    // chunkBase, M_W and the -64 halo are multiples of 16, so each group is
    // either fully in-range or fully out-of-range (OOB -> 0 bits, matching
    // -inf max-pool padding: every window has >=26 valid elements).
    const float4* wm4 = (const float4*)wm;
    #pragma unroll
    for (int it = 0; it < 5; ++it) {
        const int g = it * 256 + tid;
        if (g < NGROUPS) {                          // wave-uniform except it==4
            const int jlo = chunkBase - 64 + g * 16;
            unsigned bits = 0;
            if (jlo >= 0 && jlo < M_W) {
                const int f4 = jlo >> 2;            // float4 index
                #pragma unroll
                for (int c = 0; c < 4; ++c) {
                    const float4 v = wm4[f4 + c];
                    bits |= (unsigned)(__builtin_fabsf(v.x - x) < THRESH) << (c * 4 + 0);
                    bits |= (unsigned)(__builtin_fabsf(v.y - x) < THRESH) << (c * 4 + 1);
                    bits |= (unsigned)(__builtin_fabsf(v.z - x) < THRESH) << (c * 4 + 2);
                    bits |= (unsigned)(__builtin_fabsf(v.w - x) < THRESH) << (c * 4 + 3);
                }
            }
            preds[g] = (unsigned short)bits;
        }
    }
    __syncthreads();

    // ---- Phase 2: word build (8 B LDS read: 4 little-endian ushorts == u64)
    // + radius-25 dilation. Raw word w covers j = chunkBase - 64 + 64*w .. +63.
    // Dilated word t needs raw words t, t+1, t+2:
    //   y bit q = raw stream bit (t*64 + 39 + q), q in [0,128)
    //   out bit i = OR_{u=0..50} y bit (i+u).
    {
        const int t = tid;                               // 0..255
        const unsigned long long lo  = *(const unsigned long long*)&preds[4 * t];
        const unsigned long long mid = *(const unsigned long long*)&preds[4 * t + 4];
        const unsigned long long hi  = *(const unsigned long long*)&preds[4 * t + 8];
        __uint128_t z = ((__uint128_t)(lo >> 39))
                      | ((__uint128_t)mid << 25)
                      | ((__uint128_t)hi << 89);
        z |= z >> 1;
        z |= z >> 2;
        z |= z >> 4;
        z |= z >> 8;
        z |= z >> 16;
        z |= z >> 19;   // union covers shifts 0..50
        dil[t] = (unsigned long long)z;
    }
    __syncthreads();

    // ---- Phase 3: expand bits -> fp32, coalesced uint4 stores (1 KB/wave).
    uint4* orow = (uint4*)(out + (long long)row * M_W + chunkBase);
    #pragma unroll
    for (int it = 0; it < CHUNK / 1024; ++it) {
        const int e = it * 1024 + tid * 4;              // element offset, 4 bits/thread
        const unsigned long long wbits = dil[e >> 6];   // 16 lanes broadcast same word
        const unsigned b4 = (unsigned)(wbits >> (e & 63)) & 0xFu;
        uint4 v;
        v.x = (b4 & 1u) ? 0x3F800000u : 0u;
        v.y = (b4 & 2u) ? 0x3F800000u : 0u;
        v.z = (b4 & 4u) ? 0x3F800000u : 0u;
        v.w = (b4 & 8u) ? 0x3F800000u : 0u;
        orow[e >> 2] = v;
    }
}

extern "C" void kernel_launch(void* const* d_in, const int* in_sizes, int n_in,
                              void* d_out, int out_size, void* d_ws, size_t ws_size,
                              hipStream_t stream) {
    const float* in = (const float*)d_in[0];    // input_features (2,512) fp32
    const float* wm = (const float*)d_in[1];    // weight_matrix (512,512) fp32
    float* out = (float*)d_out;

    dim3 grid(M_W / CHUNK, N_ROWS);             // (16, 1024) = 16384 blocks
    cll_fused2_kernel<<<grid, 256, 0, stream>>>(in, wm, out);
}